// Round 8
// baseline (149.601 us; speedup 1.0000x reference)
//
#include <hip/hip_runtime.h>

// MHA: B=4, S=2048, D=512, H=8, DH=64. fp32 in/out, f16 MFMA internally.
typedef _Float16 half8  __attribute__((ext_vector_type(8)));
typedef _Float16 half4v __attribute__((ext_vector_type(4)));
typedef _Float16 half2v __attribute__((ext_vector_type(2)));
typedef float    float4v __attribute__((ext_vector_type(4)));

#define CSC 0.18033688f  /* DH^-0.5 * log2(e) */

#define WAITV0 asm volatile("s_waitcnt vmcnt(0)" ::: "memory")
#define WAITL0 asm volatile("s_waitcnt lgkmcnt(0)" ::: "memory")

__device__ __forceinline__ void async16(const _Float16* g, void* l) {
    __builtin_amdgcn_global_load_lds((const __attribute__((address_space(1))) void*)g,
                                     (__attribute__((address_space(3))) void*)l, 16, 0, 0);
}

__device__ __forceinline__ half2v pk2(float a, float b) {
    return __builtin_bit_cast(half2v, __builtin_amdgcn_cvt_pkrtz(a, b));
}

// ---------------- fused prep: blocks [0,4096) cast x -> f16; [4096,4288) transpose W ----------------
__global__ __launch_bounds__(256) void mha_prep(const float* __restrict__ x,
    const float* __restrict__ wq, const float* __restrict__ wk, const float* __restrict__ wv,
    _Float16* __restrict__ xh, _Float16* __restrict__ wt) {
    __shared__ __align__(16) _Float16 T[64][72];  // [dh][dl], padded (W branch only)
    const int tid = threadIdx.x;
    if (blockIdx.x < 4096) {
        int t = blockIdx.x * 256 + tid;  // 1048576 float4s
        float4v v = ((const float4v*)x)[t];
        half4v o;
        #pragma unroll
        for (int i = 0; i < 4; ++i) o[i] = (_Float16)v[i];
        ((half4v*)xh)[t] = o;
        return;
    }
    const int blk = blockIdx.x - 4096;        // 192 = mat(3) x h(8) x dtile(8)
    const int dt = blk & 7, h = (blk >> 3) & 7, mat = blk >> 6;
    const float* w = ((mat == 0) ? wq : (mat == 1) ? wk : wv) + h * 32768 + dt * 64 * 64;
    #pragma unroll
    for (int i = 0; i < 4; ++i) {
        int s = tid + i * 256;                // 0..1023: dl = s>>4, c4 = s&15
        int dl = s >> 4, c4 = s & 15;
        float4v v = ((const float4v*)(w + (size_t)dl * 64))[c4];
        #pragma unroll
        for (int e = 0; e < 4; ++e) T[c4 * 4 + e][dl] = (_Float16)v[e];
    }
    __syncthreads();
    #pragma unroll
    for (int i = 0; i < 2; ++i) {
        int s = tid + i * 256;                // 0..511: dh = s>>3, c8 = s&7
        int dh = s >> 3, c8 = s & 7;
        half8 o;
        #pragma unroll
        for (int e = 0; e < 8; ++e) o[e] = T[dh][c8 * 8 + e];
        *(half8*)(wt + (size_t)((mat * 8 + h) * 64 + dh) * 512 + dt * 64 + c8 * 8) = o;
    }
}

// ---------------- QKV projection: C[8192][1536] = xh[8192][512] * Wt^T ----------------
__global__ __launch_bounds__(256, 3) void mha_qkv(const _Float16* __restrict__ xh,
    const _Float16* __restrict__ wt, _Float16* __restrict__ Qm, _Float16* __restrict__ Km,
    _Float16* __restrict__ Vt) {
    __shared__ __align__(16) char smem[34816];  // staging: A[0:16K) B[16K:32K); epilogue: 128x272B
    _Float16* Ash[2] = { (_Float16*)smem,           (_Float16*)(smem + 8192)  };
    _Float16* Bsh[2] = { (_Float16*)(smem + 16384), (_Float16*)(smem + 24576) };
    const int tid = threadIdx.x;
    const int lane = tid & 63, wave = tid >> 6;
    const int quad = lane >> 4, li = lane & 15;
    const int m0 = blockIdx.x * 128, n0 = blockIdx.y * 128;
    float4v acc[4][4] = {};
    const int r0 = tid >> 2, c0 = (tid & 3) ^ ((r0 >> 1) & 3);
    const int s1 = 256 + tid, r1 = s1 >> 2, c1 = (s1 & 3) ^ ((r1 >> 1) & 3);
    const _Float16* gA0 = xh + (size_t)(m0 + r0) * 512 + c0 * 8;
    const _Float16* gA1 = xh + (size_t)(m0 + r1) * 512 + c1 * 8;
    const _Float16* gB0 = wt + (size_t)(n0 + r0) * 512 + c0 * 8;
    const _Float16* gB1 = wt + (size_t)(n0 + r1) * 512 + c1 * 8;
    const int wr = (wave >> 1) * 64, wc = (wave & 1) * 64;
    const char* aB[2]; const char* bB[2];
    #pragma unroll
    for (int bb = 0; bb < 2; ++bb) {
        aB[bb] = (const char*)Ash[bb] + (wr + li) * 64 + ((quad ^ ((li >> 1) & 3)) << 4);
        bB[bb] = (const char*)Bsh[bb] + (wc + li) * 64 + ((quad ^ ((li >> 1) & 3)) << 4);
    }
    auto stage = [&](int bb, int kk) {
        async16(gA0 + kk, (char*)Ash[bb] + wave * 1024);
        async16(gA1 + kk, (char*)Ash[bb] + 4096 + wave * 1024);
        async16(gB0 + kk, (char*)Bsh[bb] + wave * 1024);
        async16(gB1 + kk, (char*)Bsh[bb] + 4096 + wave * 1024);
    };
    auto compute = [&](int bb) {
        half8 af[4], bf[4];
        #pragma unroll
        for (int mt = 0; mt < 4; ++mt) af[mt] = *(const half8*)(aB[bb] + mt * 1024);
        #pragma unroll
        for (int nt = 0; nt < 4; ++nt) bf[nt] = *(const half8*)(bB[bb] + nt * 1024);
        #pragma unroll
        for (int mt = 0; mt < 4; ++mt)
            #pragma unroll
            for (int nt = 0; nt < 4; ++nt)
                acc[mt][nt] = __builtin_amdgcn_mfma_f32_16x16x32_f16(af[mt], bf[nt], acc[mt][nt], 0, 0, 0);
    };
    stage(0, 0);
    for (int kk = 0; kk < 512; kk += 64) {
        __syncthreads();
        stage(1, kk + 32);
        compute(0);
        __syncthreads();
        if (kk + 64 < 512) stage(0, kk + 64);
        compute(1);
    }
    const int mat = n0 >> 9;  // 0=Q 1=K 2=V (uniform per block)
    if (mat == 2) {  // V^T[bh][dh][s]: 8B stores along s
        #pragma unroll
        for (int mt = 0; mt < 4; ++mt) {
            int m = m0 + wr + mt * 16 + quad * 4;
            int b = m >> 11, s = m & 2047;
            #pragma unroll
            for (int nt = 0; nt < 4; ++nt) {
                int n = n0 + wc + nt * 16 + li;
                int h = (n >> 6) & 7, dh = n & 63;
                int bh = b * 8 + h;
                half4v pkv;
                #pragma unroll
                for (int r = 0; r < 4; ++r) pkv[r] = (_Float16)acc[mt][nt][r];
                *(half4v*)(Vt + ((size_t)bh * 64 + dh) * 2048 + s) = pkv;
            }
        }
    } else {  // Q/K: transpose tile through LDS, then 16B coalesced stores
        _Float16* dst = (mat == 0) ? Qm : Km;
        const float osc = (mat == 0) ? CSC : 1.0f;  // fold scale*log2e into Q
        __syncthreads();  // staging LDS no longer needed by any wave
        char* Tb = smem;  // 128 rows x 272 B (128 f16 + 16B pad)
        #pragma unroll
        for (int mt = 0; mt < 4; ++mt) {
            int rbase = wr + mt * 16 + quad * 4;
            #pragma unroll
            for (int nt = 0; nt < 4; ++nt) {
                int col = wc + nt * 16 + li;
                #pragma unroll
                for (int r = 0; r < 4; ++r)
                    *(_Float16*)(Tb + (rbase + r) * 272 + col * 2) = (_Float16)(acc[mt][nt][r] * osc);
            }
        }
        __syncthreads();
        const int h0 = (n0 >> 6) & 7;  // base head of this 128-col tile (h0, h0+1)
        #pragma unroll
        for (int i = 0; i < 8; ++i) {
            int c = i * 256 + tid;     // 0..2047 chunks of 16B
            int row = c >> 4, j8 = c & 15;
            half8 v = *(const half8*)(Tb + row * 272 + j8 * 16);
            int m = m0 + row;
            int b = m >> 11, s = m & 2047;
            int bh = b * 8 + h0 + (j8 >> 3);
            *(half8*)(dst + ((size_t)bh * 2048 + s) * 64 + (j8 & 7) * 8) = v;
        }
    }
}

// ---------------- flash attention: 4 independent waves/SIMD, homogeneous DMA ----------------
// R20: R1/R4/R7 all ~45us (compiler canonicalizes the schedule; 2 indep waves/SIMD can't
// cover the chains). R5's occupancy lever was right but its V register-loads shared vmcnt
// with K-DMA and got drained each tile. Fix: BOTH K and V staged via async16 into a single-
// buffered 8KB/wave arena (R4-verified layouts), 8 loads + one WAITV0 per tile (stage->use
// gap = one tile of compute). 32q/wave, block = 4 waves (2hh x 2strm) = 32KB LDS, grid
// 1024 = 4 blocks/CU -> 16 independent waves/CU (4/SIMD). launch_bounds caps VGPR at 128.
__global__ __launch_bounds__(256, 4) void mha_attn(const _Float16* __restrict__ Qm,
    const _Float16* __restrict__ Km, const _Float16* __restrict__ Vt, float* __restrict__ out) {
    __shared__ __align__(16) char smem[32768];   // 4 waves x 8KB arenas; merge reuses [0,25K)
    const int tid = threadIdx.x, lane = tid & 63, wave = tid >> 6;
    const int quad = lane >> 4, li = lane & 15;
    const int strm = wave & 1, hh = wave >> 1;
    const int flat = blockIdx.x;
    // XCD pinning: h = flat&7 -> each XCD serves one h (4 bh = 2MB K/V, L2-resident)
    const int h = flat & 7, rr = flat >> 3;
    const int qg = rr & 31, b = rr >> 5;
    const int bh = b * 8 + h;
    const _Float16* Qg = Qm + (size_t)bh * 2048 * 64;
    const _Float16* Kg = Km + (size_t)bh * 2048 * 64 + (size_t)strm * 1024 * 64;
    const _Float16* Vg = Vt + (size_t)bh * 64 * 2048 + (size_t)strm * 1024;
    const int q0 = qg * 64 + hh * 32;   // wave handles 32 q (2 tiles of 16)
    half8 qf[2][2];
    #pragma unroll
    for (int qt = 0; qt < 2; ++qt)
        #pragma unroll
        for (int ds = 0; ds < 2; ++ds)
            qf[qt][ds] = *(const half8*)(Qg + (size_t)(q0 + qt * 16 + li) * 64 + ds * 32 + quad * 8);
    WAITV0;  // drain Q loads so staging vmcnt arithmetic is exact
    half8 vone;
    #pragma unroll
    for (int e = 0; e < 8; ++e) vone[e] = (_Float16)1.0f;
    float4v O[2][4] = {};
    float4v O4[2] = {};          // row-sums of exp(S) via mfma(P, ones)
    // ---- per-wave staging pointers (R4-verified pre-swizzled sources, linear LDS dests) ----
    const int ls = lane >> 3, l7 = lane & 7;
    const _Float16* pKe = Kg + ls * 64 + ((l7 ^ (ls & 3)) << 3);
    const _Float16* pKo = Kg + (ls + 8) * 64 + (((l7 ^ (ls & 3)) ^ 4) << 3);
    const int gsl = l7 ^ ls;
    const _Float16* pV = Vg + (size_t)(ls + ((gsl >> 2) << 5)) * 2048 + ((gsl & 3) << 3);
    char* const base = smem + wave * 8192;
    char* const dstK = base;            // 4KB: one 32-kpos K tile
    char* const dstV = base + 4096;     // 4KB: one 32-kpos V tile
    // ---- fragment read addresses (R4-verified) ----
    const int rowE = ((li >> 2) << 3) | (li & 3);
    const int swzE = (li & 3) | (((li >> 2) & 1) << 2);
    const char* k0e = dstK + rowE * 128 + ((quad ^ swzE) << 4);
    const char* k1e = dstK + rowE * 128 + (((quad + 4) ^ swzE) << 4);
    const char* vB  = dstV + li * 128;
    const int cV0 = (quad ^ (li & 7)) << 4;
    const int cV1 = ((4 + quad) ^ (li & 7)) << 4;
    auto stage = [&]() {   // 8 async16 = one 32-kpos K tile + V tile; advance one tile
        async16(pKe,         dstK);
        async16(pKo,         dstK + 1024);
        async16(pKe + 1024,  dstK + 2048);
        async16(pKo + 1024,  dstK + 3072);
        async16(pV,          dstV);
        async16(pV + 16384,  dstV + 1024);
        async16(pV + 32768,  dstV + 2048);
        async16(pV + 49152,  dstV + 3072);
        pKe += 2048; pKo += 2048; pV += 32;
    };
    // ---- barrier-free main loop: 32 tiles of 32 kpos, single-buffered, WAITV0/tile ----
    stage();                       // tile 0
    #pragma unroll 1
    for (int t = 0; t < 32; ++t) {
        WAITV0;                    // tile t's 8 DMA loads have landed
        half8 f0e = *(const half8*)(k0e);
        half8 f1e = *(const half8*)(k1e);
        half8 f0o = *(const half8*)(k0e + 512);
        half8 f1o = *(const half8*)(k1e + 512);
        half8 vf0 = *(const half8*)(vB + cV0);
        half8 vf1 = *(const half8*)(vB + 2048 + cV0);
        half8 vf2 = *(const half8*)(vB + cV1);
        half8 vf3 = *(const half8*)(vB + 2048 + cV1);
        WAITL0;                    // frags in regs -> arena free for overwrite
        if (t < 31) stage();       // issue tile t+1 DMA; lands during this tile's math
        half8 pf[2];
        #pragma unroll
        for (int qt = 0; qt < 2; ++qt) {
            float4v se = {}, so = {};
            __builtin_amdgcn_s_setprio(1);
            se = __builtin_amdgcn_mfma_f32_16x16x32_f16(f0e, qf[qt][0], se, 0, 0, 0);
            se = __builtin_amdgcn_mfma_f32_16x16x32_f16(f1e, qf[qt][1], se, 0, 0, 0);
            so = __builtin_amdgcn_mfma_f32_16x16x32_f16(f0o, qf[qt][0], so, 0, 0, 0);
            so = __builtin_amdgcn_mfma_f32_16x16x32_f16(f1o, qf[qt][1], so, 0, 0, 0);
            __builtin_amdgcn_s_setprio(0);
            float pe[4], po[4];
            #pragma unroll
            for (int r = 0; r < 4; ++r) {
                pe[r] = __builtin_amdgcn_exp2f(se[r]);
                po[r] = __builtin_amdgcn_exp2f(so[r]);
            }
            half4v a = __builtin_shufflevector(pk2(pe[0], pe[1]), pk2(pe[2], pe[3]), 0, 1, 2, 3);
            half4v o = __builtin_shufflevector(pk2(po[0], po[1]), pk2(po[2], po[3]), 0, 1, 2, 3);
            pf[qt] = __builtin_shufflevector(a, o, 0, 1, 2, 3, 4, 5, 6, 7);
        }
        __builtin_amdgcn_s_setprio(1);
        #pragma unroll
        for (int qt = 0; qt < 2; ++qt)
            O4[qt] = __builtin_amdgcn_mfma_f32_16x16x32_f16(pf[qt], vone, O4[qt], 0, 0, 0);
        #pragma unroll
        for (int qt = 0; qt < 2; ++qt) {
            O[qt][0] = __builtin_amdgcn_mfma_f32_16x16x32_f16(pf[qt], vf0, O[qt][0], 0, 0, 0);
            O[qt][1] = __builtin_amdgcn_mfma_f32_16x16x32_f16(pf[qt], vf1, O[qt][1], 0, 0, 0);
            O[qt][2] = __builtin_amdgcn_mfma_f32_16x16x32_f16(pf[qt], vf2, O[qt][2], 0, 0, 0);
            O[qt][3] = __builtin_amdgcn_mfma_f32_16x16x32_f16(pf[qt], vf3, O[qt][3], 0, 0, 0);
        }
        __builtin_amdgcn_s_setprio(0);
    }
    // ---- split-K merge through LDS: strm1 waves deposit, strm0 add ----
    __syncthreads();
    float* Ob = (float*)smem;                  // [hh][2048 floats] = 2 x 8KB
    float* Lb = (float*)(smem + 24576);        // [hh][32] row-sums
    if (strm == 1) {
        #pragma unroll
        for (int qt = 0; qt < 2; ++qt) {
            #pragma unroll
            for (int dt = 0; dt < 4; ++dt)
                ((float4v*)(Ob + hh * 2048))[(qt * 4 + dt) * 64 + lane] = O[qt][dt];
            if (li == 0) {
                #pragma unroll
                for (int r = 0; r < 4; ++r)
                    Lb[hh * 32 + qt * 16 + quad * 4 + r] = O4[qt][r];
            }
        }
    }
    __syncthreads();
    if (strm == 1) return;
    #pragma unroll
    for (int qt = 0; qt < 2; ++qt) {
        #pragma unroll
        for (int dt = 0; dt < 4; ++dt) {
            float4v o2 = ((float4v*)(Ob + hh * 2048))[(qt * 4 + dt) * 64 + lane];
            O[qt][dt] += o2;
        }
        #pragma unroll
        for (int r = 0; r < 4; ++r)
            O4[qt][r] += Lb[hh * 32 + qt * 16 + quad * 4 + r];
    }
    // epilogue: out = O / l
    #pragma unroll
    for (int qt = 0; qt < 2; ++qt) {
        #pragma unroll
        for (int r = 0; r < 4; ++r) {
            float inv = 1.0f / O4[qt][r];
            int q = q0 + qt * 16 + quad * 4 + r;
            float* orow = out + ((size_t)(b * 2048 + q)) * 512 + h * 64;
            #pragma unroll
            for (int dt = 0; dt < 4; ++dt) orow[dt * 16 + li] = O[qt][dt][r] * inv;
        }
    }
}

extern "C" void kernel_launch(void* const* d_in, const int* in_sizes, int n_in,
                              void* d_out, int out_size, void* d_ws, size_t ws_size,
                              hipStream_t stream) {
    const float* x  = (const float*)d_in[0];
    const float* wq = (const float*)d_in[1];
    const float* wk = (const float*)d_in[2];
    const float* wv = (const float*)d_in[3];
    float* out = (float*)d_out;
    char* ws = (char*)d_ws;
    // ws layout (bytes): xh 8M | Wt 1.5M | Q 8M | K 8M | Vt 8M  = 35,127,296 total
    _Float16* xh = (_Float16*)(ws);
    _Float16* wt = (_Float16*)(ws + 8388608);
    _Float16* Qm = (_Float16*)(ws + 9961472);
    _Float16* Km = (_Float16*)(ws + 18350080);
    _Float16* Vt = (_Float16*)(ws + 26738688);
    if (ws_size < 35127296u) return;
    mha_prep<<<4288, 256, 0, stream>>>(x, wq, wk, wv, xh, wt);
    mha_qkv<<<dim3(64, 12), 256, 0, stream>>>(xh, wt, Qm, Km, Vt);
    mha_attn<<<1024, 256, 0, stream>>>(Qm, Km, Vt, out);
}

// Round 9
// 137.308 us; speedup vs baseline: 1.0895x; 1.0895x over previous
//
#include <hip/hip_runtime.h>

// MHA: B=4, S=2048, D=512, H=8, DH=64. fp32 in/out, f16 MFMA internally.
typedef _Float16 half8  __attribute__((ext_vector_type(8)));
typedef _Float16 half4v __attribute__((ext_vector_type(4)));
typedef _Float16 half2v __attribute__((ext_vector_type(2)));
typedef float    float4v __attribute__((ext_vector_type(4)));

#define CSC 0.18033688f  /* DH^-0.5 * log2(e) */

#define WAITV0 asm volatile("s_waitcnt vmcnt(0)" ::: "memory")
#define WAITL0 asm volatile("s_waitcnt lgkmcnt(0)" ::: "memory")

__device__ __forceinline__ void async16(const _Float16* g, void* l) {
    __builtin_amdgcn_global_load_lds((const __attribute__((address_space(1))) void*)g,
                                     (__attribute__((address_space(3))) void*)l, 16, 0, 0);
}

__device__ __forceinline__ half2v pk2(float a, float b) {
    return __builtin_bit_cast(half2v, __builtin_amdgcn_cvt_pkrtz(a, b));
}

// ---------------- fused prep: blocks [0,4096) cast x -> f16; [4096,4288) transpose W ----------------
__global__ __launch_bounds__(256) void mha_prep(const float* __restrict__ x,
    const float* __restrict__ wq, const float* __restrict__ wk, const float* __restrict__ wv,
    _Float16* __restrict__ xh, _Float16* __restrict__ wt) {
    __shared__ __align__(16) _Float16 T[64][72];  // [dh][dl], padded (W branch only)
    const int tid = threadIdx.x;
    if (blockIdx.x < 4096) {
        int t = blockIdx.x * 256 + tid;  // 1048576 float4s
        float4v v = ((const float4v*)x)[t];
        half4v o;
        #pragma unroll
        for (int i = 0; i < 4; ++i) o[i] = (_Float16)v[i];
        ((half4v*)xh)[t] = o;
        return;
    }
    const int blk = blockIdx.x - 4096;        // 192 = mat(3) x h(8) x dtile(8)
    const int dt = blk & 7, h = (blk >> 3) & 7, mat = blk >> 6;
    const float* w = ((mat == 0) ? wq : (mat == 1) ? wk : wv) + h * 32768 + dt * 64 * 64;
    #pragma unroll
    for (int i = 0; i < 4; ++i) {
        int s = tid + i * 256;                // 0..1023: dl = s>>4, c4 = s&15
        int dl = s >> 4, c4 = s & 15;
        float4v v = ((const float4v*)(w + (size_t)dl * 64))[c4];
        #pragma unroll
        for (int e = 0; e < 4; ++e) T[c4 * 4 + e][dl] = (_Float16)v[e];
    }
    __syncthreads();
    #pragma unroll
    for (int i = 0; i < 2; ++i) {
        int s = tid + i * 256;                // 0..511: dh = s>>3, c8 = s&7
        int dh = s >> 3, c8 = s & 7;
        half8 o;
        #pragma unroll
        for (int e = 0; e < 8; ++e) o[e] = T[dh][c8 * 8 + e];
        *(half8*)(wt + (size_t)((mat * 8 + h) * 64 + dh) * 512 + dt * 64 + c8 * 8) = o;
    }
}

// ---------------- QKV projection: C[8192][1536] = xh[8192][512] * Wt^T ----------------
__global__ __launch_bounds__(256, 3) void mha_qkv(const _Float16* __restrict__ xh,
    const _Float16* __restrict__ wt, _Float16* __restrict__ Qm, _Float16* __restrict__ Km,
    _Float16* __restrict__ Vt) {
    __shared__ __align__(16) char smem[34816];  // staging: A[0:16K) B[16K:32K); epilogue: 128x272B
    _Float16* Ash[2] = { (_Float16*)smem,           (_Float16*)(smem + 8192)  };
    _Float16* Bsh[2] = { (_Float16*)(smem + 16384), (_Float16*)(smem + 24576) };
    const int tid = threadIdx.x;
    const int lane = tid & 63, wave = tid >> 6;
    const int quad = lane >> 4, li = lane & 15;
    const int m0 = blockIdx.x * 128, n0 = blockIdx.y * 128;
    float4v acc[4][4] = {};
    const int r0 = tid >> 2, c0 = (tid & 3) ^ ((r0 >> 1) & 3);
    const int s1 = 256 + tid, r1 = s1 >> 2, c1 = (s1 & 3) ^ ((r1 >> 1) & 3);
    const _Float16* gA0 = xh + (size_t)(m0 + r0) * 512 + c0 * 8;
    const _Float16* gA1 = xh + (size_t)(m0 + r1) * 512 + c1 * 8;
    const _Float16* gB0 = wt + (size_t)(n0 + r0) * 512 + c0 * 8;
    const _Float16* gB1 = wt + (size_t)(n0 + r1) * 512 + c1 * 8;
    const int wr = (wave >> 1) * 64, wc = (wave & 1) * 64;
    const char* aB[2]; const char* bB[2];
    #pragma unroll
    for (int bb = 0; bb < 2; ++bb) {
        aB[bb] = (const char*)Ash[bb] + (wr + li) * 64 + ((quad ^ ((li >> 1) & 3)) << 4);
        bB[bb] = (const char*)Bsh[bb] + (wc + li) * 64 + ((quad ^ ((li >> 1) & 3)) << 4);
    }
    auto stage = [&](int bb, int kk) {
        async16(gA0 + kk, (char*)Ash[bb] + wave * 1024);
        async16(gA1 + kk, (char*)Ash[bb] + 4096 + wave * 1024);
        async16(gB0 + kk, (char*)Bsh[bb] + wave * 1024);
        async16(gB1 + kk, (char*)Bsh[bb] + 4096 + wave * 1024);
    };
    auto compute = [&](int bb) {
        half8 af[4], bf[4];
        #pragma unroll
        for (int mt = 0; mt < 4; ++mt) af[mt] = *(const half8*)(aB[bb] + mt * 1024);
        #pragma unroll
        for (int nt = 0; nt < 4; ++nt) bf[nt] = *(const half8*)(bB[bb] + nt * 1024);
        #pragma unroll
        for (int mt = 0; mt < 4; ++mt)
            #pragma unroll
            for (int nt = 0; nt < 4; ++nt)
                acc[mt][nt] = __builtin_amdgcn_mfma_f32_16x16x32_f16(af[mt], bf[nt], acc[mt][nt], 0, 0, 0);
    };
    stage(0, 0);
    for (int kk = 0; kk < 512; kk += 64) {
        __syncthreads();
        stage(1, kk + 32);
        compute(0);
        __syncthreads();
        if (kk + 64 < 512) stage(0, kk + 64);
        compute(1);
    }
    const int mat = n0 >> 9;  // 0=Q 1=K 2=V (uniform per block)
    if (mat == 2) {  // V^T[bh][dh][s]: 8B stores along s
        #pragma unroll
        for (int mt = 0; mt < 4; ++mt) {
            int m = m0 + wr + mt * 16 + quad * 4;
            int b = m >> 11, s = m & 2047;
            #pragma unroll
            for (int nt = 0; nt < 4; ++nt) {
                int n = n0 + wc + nt * 16 + li;
                int h = (n >> 6) & 7, dh = n & 63;
                int bh = b * 8 + h;
                half4v pkv;
                #pragma unroll
                for (int r = 0; r < 4; ++r) pkv[r] = (_Float16)acc[mt][nt][r];
                *(half4v*)(Vt + ((size_t)bh * 64 + dh) * 2048 + s) = pkv;
            }
        }
    } else {  // Q/K: transpose tile through LDS, then 16B coalesced stores
        _Float16* dst = (mat == 0) ? Qm : Km;
        const float osc = (mat == 0) ? CSC : 1.0f;  // fold scale*log2e into Q
        __syncthreads();  // staging LDS no longer needed by any wave
        char* Tb = smem;  // 128 rows x 272 B (128 f16 + 16B pad)
        #pragma unroll
        for (int mt = 0; mt < 4; ++mt) {
            int rbase = wr + mt * 16 + quad * 4;
            #pragma unroll
            for (int nt = 0; nt < 4; ++nt) {
                int col = wc + nt * 16 + li;
                #pragma unroll
                for (int r = 0; r < 4; ++r)
                    *(_Float16*)(Tb + (rbase + r) * 272 + col * 2) = (_Float16)(acc[mt][nt][r] * osc);
            }
        }
        __syncthreads();
        const int h0 = (n0 >> 6) & 7;  // base head of this 128-col tile (h0, h0+1)
        #pragma unroll
        for (int i = 0; i < 8; ++i) {
            int c = i * 256 + tid;     // 0..2047 chunks of 16B
            int row = c >> 4, j8 = c & 15;
            half8 v = *(const half8*)(Tb + row * 272 + j8 * 16);
            int m = m0 + row;
            int b = m >> 11, s = m & 2047;
            int bh = b * 8 + h0 + (j8 >> 3);
            *(half8*)(dst + ((size_t)bh * 2048 + s) * 64 + (j8 & 7) * 8) = v;
        }
    }
}

// ---------------- flash attention: R4 skeleton, paired-tile loop ----------------
// R21: occupancy lever exhausted (R2 lockstep-neutral, R5/R8 regress via slack+fixed-overhead).
// Machine model: MFMA blocks its wave -> per wave-tile time = MFMA + VALU + stall, serial.
// Attack the stall+fixed terms: process 2 tiles per iteration with ONE vmcnt wait, ONE
// ds_read burst (16x b128), ONE lgkm wait, ONE 16-load stage per pair. DMA slack >= 1 full
// pair (~3000 cyc); ds latency amortized once per pair. Math identical to R4 (44.8us).
__global__ __launch_bounds__(256, 2) void mha_attn(const _Float16* __restrict__ Qm,
    const _Float16* __restrict__ Km, const _Float16* __restrict__ Vt, float* __restrict__ out) {
    __shared__ __align__(16) char smem[65536];   // 4 waves x 16KB arenas; merge reuses [0,40K)
    const int tid = threadIdx.x, lane = tid & 63, wave = tid >> 6;
    const int quad = lane >> 4, li = lane & 15;
    const int strm = wave & 1, hh = wave >> 1;
    const int flat = blockIdx.x;
    const int qb = (flat >> 3) & 15;
    const int bh = ((flat >> 7) << 3) | (flat & 7);
    const int b = bh >> 3, h = bh & 7;
    const _Float16* Qg = Qm + (size_t)bh * 2048 * 64;
    const _Float16* Kg = Km + (size_t)bh * 2048 * 64 + (size_t)strm * 1024 * 64;
    const _Float16* Vg = Vt + (size_t)bh * 64 * 2048 + (size_t)strm * 1024;
    const int q0 = qb * 128 + hh * 64;  // wave handles 64 q (4 tiles of 16)
    half8 qf[4][2];
    #pragma unroll
    for (int qt = 0; qt < 4; ++qt)
        #pragma unroll
        for (int ds = 0; ds < 2; ++ds)
            qf[qt][ds] = *(const half8*)(Qg + (size_t)(q0 + qt * 16 + li) * 64 + ds * 32 + quad * 8);
    WAITV0;  // drain Q loads so staging vmcnt arithmetic is exact
    half8 vone;
    #pragma unroll
    for (int e = 0; e < 8; ++e) vone[e] = (_Float16)1.0f;
    float4v O[4][4] = {};
    float4v O4[4] = {};          // row-sums of exp(S) via mfma(P, ones)
    // ---- per-wave staging pointers (pre-swizzled global sources, linear LDS dests) ----
    const int ls = lane >> 3, l7 = lane & 7;
    const _Float16* pKe[2]; const _Float16* pKo[2]; const _Float16* pV[2];
    pKe[0] = Kg + ls * 64 + ((l7 ^ (ls & 3)) << 3);
    pKo[0] = Kg + (ls + 8) * 64 + (((l7 ^ (ls & 3)) ^ 4) << 3);
    const int gsl = l7 ^ ls;
    pV[0] = Vg + (size_t)(ls + ((gsl >> 2) << 5)) * 2048 + ((gsl & 3) << 3);
    pKe[1] = pKe[0] + 2048;  pKo[1] = pKo[0] + 2048;  pV[1] = pV[0] + 32;  // tile 1
    char* const base = smem + wave * 16384;
    char* const dstK[2] = { base,        base + 8192  };
    char* const dstV[2] = { base + 4096, base + 12288 };
    // ---- fragment read addresses ----
    const int rowE = ((li >> 2) << 3) | (li & 3);
    const int swzE = (li & 3) | (((li >> 2) & 1) << 2);
    const char *k0e[2], *k1e[2], *vB[2];
    #pragma unroll
    for (int bb = 0; bb < 2; ++bb) {
        k0e[bb] = dstK[bb] + rowE * 128 + ((quad ^ swzE) << 4);
        k1e[bb] = dstK[bb] + rowE * 128 + (((quad + 4) ^ swzE) << 4);
        vB[bb]  = dstV[bb] + li * 128;
    }
    const int cV0 = (quad ^ (li & 7)) << 4;
    const int cV1 = ((4 + quad) ^ (li & 7)) << 4;
    auto stage = [&](int bb) {   // 8 async16 = one 32-kpos K tile + V tile for this wave
        async16(pKe[bb],         dstK[bb]);
        async16(pKo[bb],         dstK[bb] + 1024);
        async16(pKe[bb] + 1024,  dstK[bb] + 2048);
        async16(pKo[bb] + 1024,  dstK[bb] + 3072);
        async16(pV[bb],          dstV[bb]);
        async16(pV[bb] + 16384,  dstV[bb] + 1024);
        async16(pV[bb] + 32768,  dstV[bb] + 2048);
        async16(pV[bb] + 49152,  dstV[bb] + 3072);
        pKe[bb] += 4096; pKo[bb] += 4096; pV[bb] += 64;   // advance 2 tiles (64 kpos)
    };
    // compute one 32-kpos tile from register frags (math identical to R4)
    auto computeT = [&](half8 f0e, half8 f1e, half8 f0o, half8 f1o,
                        half8 vf0, half8 vf1, half8 vf2, half8 vf3) {
        half8 pf[4];
        #pragma unroll
        for (int qt = 0; qt < 4; ++qt) {
            float4v se = {}, so = {};
            __builtin_amdgcn_s_setprio(1);
            se = __builtin_amdgcn_mfma_f32_16x16x32_f16(f0e, qf[qt][0], se, 0, 0, 0);
            se = __builtin_amdgcn_mfma_f32_16x16x32_f16(f1e, qf[qt][1], se, 0, 0, 0);
            so = __builtin_amdgcn_mfma_f32_16x16x32_f16(f0o, qf[qt][0], so, 0, 0, 0);
            so = __builtin_amdgcn_mfma_f32_16x16x32_f16(f1o, qf[qt][1], so, 0, 0, 0);
            __builtin_amdgcn_s_setprio(0);
            float pe[4], po[4];
            #pragma unroll
            for (int r = 0; r < 4; ++r) {
                pe[r] = __builtin_amdgcn_exp2f(se[r]);
                po[r] = __builtin_amdgcn_exp2f(so[r]);
            }
            half4v a = __builtin_shufflevector(pk2(pe[0], pe[1]), pk2(pe[2], pe[3]), 0, 1, 2, 3);
            half4v o = __builtin_shufflevector(pk2(po[0], po[1]), pk2(po[2], po[3]), 0, 1, 2, 3);
            pf[qt] = __builtin_shufflevector(a, o, 0, 1, 2, 3, 4, 5, 6, 7);
        }
        __builtin_amdgcn_s_setprio(1);
        #pragma unroll
        for (int qt = 0; qt < 4; ++qt)
            O4[qt] = __builtin_amdgcn_mfma_f32_16x16x32_f16(pf[qt], vone, O4[qt], 0, 0, 0);
        #pragma unroll
        for (int qt = 0; qt < 4; ++qt) {
            O[qt][0] = __builtin_amdgcn_mfma_f32_16x16x32_f16(pf[qt], vf0, O[qt][0], 0, 0, 0);
            O[qt][1] = __builtin_amdgcn_mfma_f32_16x16x32_f16(pf[qt], vf1, O[qt][1], 0, 0, 0);
            O[qt][2] = __builtin_amdgcn_mfma_f32_16x16x32_f16(pf[qt], vf2, O[qt][2], 0, 0, 0);
            O[qt][3] = __builtin_amdgcn_mfma_f32_16x16x32_f16(pf[qt], vf3, O[qt][3], 0, 0, 0);
        }
        __builtin_amdgcn_s_setprio(0);
    };
    // ---- paired-tile main loop: 16 pairs x 2 tiles of 32 kpos ----
    stage(0);          // tile 0
    stage(1);          // tile 1  (16 loads outstanding)
    #pragma unroll 1
    for (int p = 0; p < 16; ++p) {
        WAITV0;        // pair p's 16 DMA loads landed (issued >= 1 pair ago)
        // burst-read all 16 frags for both tiles
        half8 fA0e = *(const half8*)(k0e[0]);
        half8 fA1e = *(const half8*)(k1e[0]);
        half8 fA0o = *(const half8*)(k0e[0] + 512);
        half8 fA1o = *(const half8*)(k1e[0] + 512);
        half8 vA0  = *(const half8*)(vB[0] + cV0);
        half8 vA1  = *(const half8*)(vB[0] + 2048 + cV0);
        half8 vA2  = *(const half8*)(vB[0] + cV1);
        half8 vA3  = *(const half8*)(vB[0] + 2048 + cV1);
        half8 fB0e = *(const half8*)(k0e[1]);
        half8 fB1e = *(const half8*)(k1e[1]);
        half8 fB0o = *(const half8*)(k0e[1] + 512);
        half8 fB1o = *(const half8*)(k1e[1] + 512);
        half8 vB0  = *(const half8*)(vB[1] + cV0);
        half8 vB1  = *(const half8*)(vB[1] + 2048 + cV0);
        half8 vB2  = *(const half8*)(vB[1] + cV1);
        half8 vB3  = *(const half8*)(vB[1] + 2048 + cV1);
        WAITL0;        // all frags in regs -> arenas free for overwrite
        if (p < 15) { stage(0); stage(1); }   // issue pair p+1 (16 loads in flight)
        computeT(fA0e, fA1e, fA0o, fA1o, vA0, vA1, vA2, vA3);
        computeT(fB0e, fB1e, fB0o, fB1o, vB0, vB1, vB2, vB3);
    }
    // ---- split-K merge through LDS: strm1 waves deposit, strm0 add ----
    __syncthreads();
    float* Obuf = (float*)smem;                 // 2 hh x 16KB
    float* Lbuf = (float*)(smem + 32768);       // 2 hh x 4KB
    if (strm == 1) {
        #pragma unroll
        for (int qt = 0; qt < 4; ++qt) {
            #pragma unroll
            for (int dt = 0; dt < 4; ++dt)
                ((float4v*)(Obuf + hh * 4096))[(qt * 4 + dt) * 64 + lane] = O[qt][dt];
            ((float4v*)(Lbuf + hh * 1024))[qt * 64 + lane] = O4[qt];
        }
    }
    __syncthreads();
    if (strm == 1) return;
    #pragma unroll
    for (int qt = 0; qt < 4; ++qt) {
        #pragma unroll
        for (int dt = 0; dt < 4; ++dt) {
            float4v o2 = ((float4v*)(Obuf + hh * 4096))[(qt * 4 + dt) * 64 + lane];
            O[qt][dt] += o2;
        }
        float4v l2 = ((float4v*)(Lbuf + hh * 1024))[qt * 64 + lane];
        O4[qt] += l2;
    }
    // epilogue: out = O / l  (l for this lane's quad rows sits in O4[qt][r])
    #pragma unroll
    for (int qt = 0; qt < 4; ++qt) {
        #pragma unroll
        for (int r = 0; r < 4; ++r) {
            float inv = 1.0f / O4[qt][r];
            int q = q0 + qt * 16 + quad * 4 + r;
            float* orow = out + ((size_t)(b * 2048 + q)) * 512 + h * 64;
            #pragma unroll
            for (int dt = 0; dt < 4; ++dt) orow[dt * 16 + li] = O[qt][dt][r] * inv;
        }
    }
}

extern "C" void kernel_launch(void* const* d_in, const int* in_sizes, int n_in,
                              void* d_out, int out_size, void* d_ws, size_t ws_size,
                              hipStream_t stream) {
    const float* x  = (const float*)d_in[0];
    const float* wq = (const float*)d_in[1];
    const float* wk = (const float*)d_in[2];
    const float* wv = (const float*)d_in[3];
    float* out = (float*)d_out;
    char* ws = (char*)d_ws;
    // ws layout (bytes): xh 8M | Wt 1.5M | Q 8M | K 8M | Vt 8M  = 35,127,296 total
    _Float16* xh = (_Float16*)(ws);
    _Float16* wt = (_Float16*)(ws + 8388608);
    _Float16* Qm = (_Float16*)(ws + 9961472);
    _Float16* Km = (_Float16*)(ws + 18350080);
    _Float16* Vt = (_Float16*)(ws + 26738688);
    if (ws_size < 35127296u) return;
    mha_prep<<<4288, 256, 0, stream>>>(x, wq, wk, wv, xh, wt);
    mha_qkv<<<dim3(64, 12), 256, 0, stream>>>(xh, wt, Qm, Km, Vt);
    mha_attn<<<512, 256, 0, stream>>>(Qm, Km, Vt, out);
}

// Round 11
// 134.316 us; speedup vs baseline: 1.1138x; 1.0223x over previous
//
#include <hip/hip_runtime.h>

// MHA: B=4, S=2048, D=512, H=8, DH=64. fp32 in/out, f16 MFMA internally.
typedef _Float16 half8  __attribute__((ext_vector_type(8)));
typedef _Float16 half4v __attribute__((ext_vector_type(4)));
typedef _Float16 half2v __attribute__((ext_vector_type(2)));
typedef float    float4v __attribute__((ext_vector_type(4)));

#define CSC 0.18033688f  /* DH^-0.5 * log2(e) */

#define WAITV8 asm volatile("s_waitcnt vmcnt(8)" ::: "memory")
#define WAITV0 asm volatile("s_waitcnt vmcnt(0)" ::: "memory")
#define WAITL0 asm volatile("s_waitcnt lgkmcnt(0)" ::: "memory")

__device__ __forceinline__ void async16(const _Float16* g, void* l) {
    __builtin_amdgcn_global_load_lds((const __attribute__((address_space(1))) void*)g,
                                     (__attribute__((address_space(3))) void*)l, 16, 0, 0);
}

__device__ __forceinline__ half2v pk2(float a, float b) {
    return __builtin_bit_cast(half2v, __builtin_amdgcn_cvt_pkrtz(a, b));
}

// ---------------- fused prep: blocks [0,4096) cast x -> f16; [4096,4288) transpose W ----------------
__global__ __launch_bounds__(256) void mha_prep(const float* __restrict__ x,
    const float* __restrict__ wq, const float* __restrict__ wk, const float* __restrict__ wv,
    _Float16* __restrict__ xh, _Float16* __restrict__ wt) {
    __shared__ __align__(16) _Float16 T[64][72];  // [dh][dl], padded (W branch only)
    const int tid = threadIdx.x;
    if (blockIdx.x < 4096) {
        int t = blockIdx.x * 256 + tid;  // 1048576 float4s
        float4v v = ((const float4v*)x)[t];
        half4v o;
        #pragma unroll
        for (int i = 0; i < 4; ++i) o[i] = (_Float16)v[i];
        ((half4v*)xh)[t] = o;
        return;
    }
    const int blk = blockIdx.x - 4096;        // 192 = mat(3) x h(8) x dtile(8)
    const int dt = blk & 7, h = (blk >> 3) & 7, mat = blk >> 6;
    const float* w = ((mat == 0) ? wq : (mat == 1) ? wk : wv) + h * 32768 + dt * 64 * 64;
    #pragma unroll
    for (int i = 0; i < 4; ++i) {
        int s = tid + i * 256;                // 0..1023: dl = s>>4, c4 = s&15
        int dl = s >> 4, c4 = s & 15;
        float4v v = ((const float4v*)(w + (size_t)dl * 64))[c4];
        #pragma unroll
        for (int e = 0; e < 4; ++e) T[c4 * 4 + e][dl] = (_Float16)v[e];
    }
    __syncthreads();
    #pragma unroll
    for (int i = 0; i < 2; ++i) {
        int s = tid + i * 256;                // 0..511: dh = s>>3, c8 = s&7
        int dh = s >> 3, c8 = s & 7;
        half8 o;
        #pragma unroll
        for (int e = 0; e < 8; ++e) o[e] = T[dh][c8 * 8 + e];
        *(half8*)(wt + (size_t)((mat * 8 + h) * 64 + dh) * 512 + dt * 64 + c8 * 8) = o;
    }
}

// ---------------- QKV projection: C[8192][1536] = xh[8192][512] * Wt^T ----------------
// R22: 1D grid with m-panel->XCD chunking: XCD x owns m-panels [8x,8x+8) x all 12 n-blocks.
// Per-XCD L2 working set = 8x128KB (A) + 1.5MB (full Wt) = 2.5MB < 4MB -> A fetched once
// per XCD, B fully L2-resident (T1). Bijective since 768%8==0. Kernel body unchanged.
__global__ __launch_bounds__(256, 3) void mha_qkv(const _Float16* __restrict__ xh,
    const _Float16* __restrict__ wt, _Float16* __restrict__ Qm, _Float16* __restrict__ Km,
    _Float16* __restrict__ Vt) {
    __shared__ __align__(16) char smem[34816];  // staging: A[0:16K) B[16K:32K); epilogue: 128x272B
    _Float16* Ash[2] = { (_Float16*)smem,           (_Float16*)(smem + 8192)  };
    _Float16* Bsh[2] = { (_Float16*)(smem + 16384), (_Float16*)(smem + 24576) };
    const int tid = threadIdx.x;
    const int lane = tid & 63, wave = tid >> 6;
    const int quad = lane >> 4, li = lane & 15;
    const int bid = blockIdx.x;                 // 768 blocks
    const int xcd = bid & 7, ii = bid >> 3;     // ii in 0..95
    const int m0 = (xcd * 8 + (ii & 7)) * 128;  // m-panel pinned to XCD
    const int n0 = (ii >> 3) * 128;             // n-block 0..11
    float4v acc[4][4] = {};
    const int r0 = tid >> 2, c0 = (tid & 3) ^ ((r0 >> 1) & 3);
    const int s1 = 256 + tid, r1 = s1 >> 2, c1 = (s1 & 3) ^ ((r1 >> 1) & 3);
    const _Float16* gA0 = xh + (size_t)(m0 + r0) * 512 + c0 * 8;
    const _Float16* gA1 = xh + (size_t)(m0 + r1) * 512 + c1 * 8;
    const _Float16* gB0 = wt + (size_t)(n0 + r0) * 512 + c0 * 8;
    const _Float16* gB1 = wt + (size_t)(n0 + r1) * 512 + c1 * 8;
    const int wr = (wave >> 1) * 64, wc = (wave & 1) * 64;
    const char* aB[2]; const char* bB[2];
    #pragma unroll
    for (int bb = 0; bb < 2; ++bb) {
        aB[bb] = (const char*)Ash[bb] + (wr + li) * 64 + ((quad ^ ((li >> 1) & 3)) << 4);
        bB[bb] = (const char*)Bsh[bb] + (wc + li) * 64 + ((quad ^ ((li >> 1) & 3)) << 4);
    }
    auto stage = [&](int bb, int kk) {
        async16(gA0 + kk, (char*)Ash[bb] + wave * 1024);
        async16(gA1 + kk, (char*)Ash[bb] + 4096 + wave * 1024);
        async16(gB0 + kk, (char*)Bsh[bb] + wave * 1024);
        async16(gB1 + kk, (char*)Bsh[bb] + 4096 + wave * 1024);
    };
    auto compute = [&](int bb) {
        half8 af[4], bf[4];
        #pragma unroll
        for (int mt = 0; mt < 4; ++mt) af[mt] = *(const half8*)(aB[bb] + mt * 1024);
        #pragma unroll
        for (int nt = 0; nt < 4; ++nt) bf[nt] = *(const half8*)(bB[bb] + nt * 1024);
        #pragma unroll
        for (int mt = 0; mt < 4; ++mt)
            #pragma unroll
            for (int nt = 0; nt < 4; ++nt)
                acc[mt][nt] = __builtin_amdgcn_mfma_f32_16x16x32_f16(af[mt], bf[nt], acc[mt][nt], 0, 0, 0);
    };
    stage(0, 0);
    for (int kk = 0; kk < 512; kk += 64) {
        __syncthreads();
        stage(1, kk + 32);
        compute(0);
        __syncthreads();
        if (kk + 64 < 512) stage(0, kk + 64);
        compute(1);
    }
    const int mat = n0 >> 9;  // 0=Q 1=K 2=V (uniform per block)
    if (mat == 2) {  // V^T[bh][dh][s]: 8B stores along s
        #pragma unroll
        for (int mt = 0; mt < 4; ++mt) {
            int m = m0 + wr + mt * 16 + quad * 4;
            int b = m >> 11, s = m & 2047;
            #pragma unroll
            for (int nt = 0; nt < 4; ++nt) {
                int n = n0 + wc + nt * 16 + li;
                int h = (n >> 6) & 7, dh = n & 63;
                int bh = b * 8 + h;
                half4v pkv;
                #pragma unroll
                for (int r = 0; r < 4; ++r) pkv[r] = (_Float16)acc[mt][nt][r];
                *(half4v*)(Vt + ((size_t)bh * 64 + dh) * 2048 + s) = pkv;
            }
        }
    } else {  // Q/K: transpose tile through LDS, then 16B coalesced stores
        _Float16* dst = (mat == 0) ? Qm : Km;
        const float osc = (mat == 0) ? CSC : 1.0f;  // fold scale*log2e into Q
        __syncthreads();  // staging LDS no longer needed by any wave
        char* Tb = smem;  // 128 rows x 272 B (128 f16 + 16B pad)
        #pragma unroll
        for (int mt = 0; mt < 4; ++mt) {
            int rbase = wr + mt * 16 + quad * 4;
            #pragma unroll
            for (int nt = 0; nt < 4; ++nt) {
                int col = wc + nt * 16 + li;
                #pragma unroll
                for (int r = 0; r < 4; ++r)
                    *(_Float16*)(Tb + (rbase + r) * 272 + col * 2) = (_Float16)(acc[mt][nt][r] * osc);
            }
        }
        __syncthreads();
        const int h0 = (n0 >> 6) & 7;  // base head of this 128-col tile (h0, h0+1)
        #pragma unroll
        for (int i = 0; i < 8; ++i) {
            int c = i * 256 + tid;     // 0..2047 chunks of 16B
            int row = c >> 4, j8 = c & 15;
            half8 v = *(const half8*)(Tb + row * 272 + j8 * 16);
            int m = m0 + row;
            int b = m >> 11, s = m & 2047;
            int bh = b * 8 + h0 + (j8 >> 3);
            *(half8*)(dst + ((size_t)bh * 2048 + s) * 64 + (j8 & 7) * 8) = v;
        }
    }
}

// ---------------- flash attention: R4 version (best measured: 44.76us) ----------------
// Attn is at the plain-HIP plateau (~860 TF vs m214 ladder ~900): R1/R3/R4/R7/R8/R9 all
// converge 44.8-46.5us. Frozen at the best variant; optimization focus moved to qkv.
__global__ __launch_bounds__(256, 2) void mha_attn(const _Float16* __restrict__ Qm,
    const _Float16* __restrict__ Km, const _Float16* __restrict__ Vt, float* __restrict__ out) {
    __shared__ __align__(16) char smem[65536];   // 4 waves x 16KB arenas; merge reuses [0,40K)
    const int tid = threadIdx.x, lane = tid & 63, wave = tid >> 6;
    const int quad = lane >> 4, li = lane & 15;
    const int strm = wave & 1, hh = wave >> 1;
    const int flat = blockIdx.x;
    const int qb = (flat >> 3) & 15;
    const int bh = ((flat >> 7) << 3) | (flat & 7);
    const int b = bh >> 3, h = bh & 7;
    const _Float16* Qg = Qm + (size_t)bh * 2048 * 64;
    const _Float16* Kg = Km + (size_t)bh * 2048 * 64 + (size_t)strm * 1024 * 64;
    const _Float16* Vg = Vt + (size_t)bh * 64 * 2048 + (size_t)strm * 1024;
    const int q0 = qb * 128 + hh * 64;  // wave handles 64 q (4 tiles of 16)
    half8 qf[4][2];
    #pragma unroll
    for (int qt = 0; qt < 4; ++qt)
        #pragma unroll
        for (int ds = 0; ds < 2; ++ds)
            qf[qt][ds] = *(const half8*)(Qg + (size_t)(q0 + qt * 16 + li) * 64 + ds * 32 + quad * 8);
    WAITV0;  // drain Q loads so staging vmcnt arithmetic is exact
    half8 vone;
    #pragma unroll
    for (int e = 0; e < 8; ++e) vone[e] = (_Float16)1.0f;
    float4v O[4][4] = {};
    float4v O4[4] = {};          // row-sums of exp(S) via mfma(P, ones)
    // ---- per-wave staging pointers (pre-swizzled global sources, linear LDS dests) ----
    const int ls = lane >> 3, l7 = lane & 7;
    const _Float16* pKe[2]; const _Float16* pKo[2]; const _Float16* pV[2];
    pKe[0] = Kg + ls * 64 + ((l7 ^ (ls & 3)) << 3);
    pKo[0] = Kg + (ls + 8) * 64 + (((l7 ^ (ls & 3)) ^ 4) << 3);
    const int gsl = l7 ^ ls;
    pV[0] = Vg + (size_t)(ls + ((gsl >> 2) << 5)) * 2048 + ((gsl & 3) << 3);
    pKe[1] = pKe[0] + 2048;  pKo[1] = pKo[0] + 2048;  pV[1] = pV[0] + 32;  // tile 1
    char* const base = smem + wave * 16384;
    char* const dstK[2] = { base,        base + 8192  };
    char* const dstV[2] = { base + 4096, base + 12288 };
    // ---- fragment read addresses ----
    const int rowE = ((li >> 2) << 3) | (li & 3);
    const int swzE = (li & 3) | (((li >> 2) & 1) << 2);
    const char *k0e[2], *k1e[2], *vB[2];
    #pragma unroll
    for (int bb = 0; bb < 2; ++bb) {
        k0e[bb] = dstK[bb] + rowE * 128 + ((quad ^ swzE) << 4);
        k1e[bb] = dstK[bb] + rowE * 128 + (((quad + 4) ^ swzE) << 4);
        vB[bb]  = dstV[bb] + li * 128;
    }
    const int cV0 = (quad ^ (li & 7)) << 4;
    const int cV1 = ((4 + quad) ^ (li & 7)) << 4;
    auto stage = [&](int bb) {   // 8 async16 = one 32-kpos K tile + V tile for this wave
        async16(pKe[bb],         dstK[bb]);
        async16(pKo[bb],         dstK[bb] + 1024);
        async16(pKe[bb] + 1024,  dstK[bb] + 2048);
        async16(pKo[bb] + 1024,  dstK[bb] + 3072);
        async16(pV[bb],          dstV[bb]);
        async16(pV[bb] + 16384,  dstV[bb] + 1024);
        async16(pV[bb] + 32768,  dstV[bb] + 2048);
        async16(pV[bb] + 49152,  dstV[bb] + 3072);
        pKe[bb] += 4096; pKo[bb] += 4096; pV[bb] += 64;   // advance 2 tiles (64 kpos)
    };
    auto tile = [&](int bb, bool doStage) {
        // issue all 8 ds_reads, land them, then fire next DMA before the math (T14)
        half8 f0e = *(const half8*)(k0e[bb]);
        half8 f1e = *(const half8*)(k1e[bb]);
        half8 f0o = *(const half8*)(k0e[bb] + 512);
        half8 f1o = *(const half8*)(k1e[bb] + 512);
        half8 vf0 = *(const half8*)(vB[bb] + cV0);
        half8 vf1 = *(const half8*)(vB[bb] + 2048 + cV0);
        half8 vf2 = *(const half8*)(vB[bb] + cV1);
        half8 vf3 = *(const half8*)(vB[bb] + 2048 + cV1);
        WAITL0;                      // frags in regs -> buffer free for overwrite
        if (doStage) stage(bb);
        half8 pf[4];
        #pragma unroll
        for (int qt = 0; qt < 4; ++qt) {
            float4v se = {}, so = {};
            __builtin_amdgcn_s_setprio(1);
            se = __builtin_amdgcn_mfma_f32_16x16x32_f16(f0e, qf[qt][0], se, 0, 0, 0);
            se = __builtin_amdgcn_mfma_f32_16x16x32_f16(f1e, qf[qt][1], se, 0, 0, 0);
            so = __builtin_amdgcn_mfma_f32_16x16x32_f16(f0o, qf[qt][0], so, 0, 0, 0);
            so = __builtin_amdgcn_mfma_f32_16x16x32_f16(f1o, qf[qt][1], so, 0, 0, 0);
            __builtin_amdgcn_s_setprio(0);
            float pe[4], po[4];
            #pragma unroll
            for (int r = 0; r < 4; ++r) {
                pe[r] = __builtin_amdgcn_exp2f(se[r]);
                po[r] = __builtin_amdgcn_exp2f(so[r]);
            }
            half4v a = __builtin_shufflevector(pk2(pe[0], pe[1]), pk2(pe[2], pe[3]), 0, 1, 2, 3);
            half4v o = __builtin_shufflevector(pk2(po[0], po[1]), pk2(po[2], po[3]), 0, 1, 2, 3);
            pf[qt] = __builtin_shufflevector(a, o, 0, 1, 2, 3, 4, 5, 6, 7);
        }
        __builtin_amdgcn_s_setprio(1);
        #pragma unroll
        for (int qt = 0; qt < 4; ++qt)
            O4[qt] = __builtin_amdgcn_mfma_f32_16x16x32_f16(pf[qt], vone, O4[qt], 0, 0, 0);
        #pragma unroll
        for (int qt = 0; qt < 4; ++qt) {
            O[qt][0] = __builtin_amdgcn_mfma_f32_16x16x32_f16(pf[qt], vf0, O[qt][0], 0, 0, 0);
            O[qt][1] = __builtin_amdgcn_mfma_f32_16x16x32_f16(pf[qt], vf1, O[qt][1], 0, 0, 0);
            O[qt][2] = __builtin_amdgcn_mfma_f32_16x16x32_f16(pf[qt], vf2, O[qt][2], 0, 0, 0);
            O[qt][3] = __builtin_amdgcn_mfma_f32_16x16x32_f16(pf[qt], vf3, O[qt][3], 0, 0, 0);
        }
        __builtin_amdgcn_s_setprio(0);
    };
    // ---- barrier-free main loop: 32 tiles of 32 kpos, dbuf, counted vmcnt ----
    stage(0);          // tile 0
    stage(1);          // tile 1  (16 loads outstanding)
    #pragma unroll 1
    for (int tp = 0; tp < 15; ++tp) {
        WAITV8; tile(0, true);    // compute 2tp,   stage 2tp+2
        WAITV8; tile(1, true);    // compute 2tp+1, stage 2tp+3
    }
    WAITV8; tile(0, false);       // tile 30
    WAITV0; tile(1, false);       // tile 31
    // ---- split-K merge through LDS: strm1 waves deposit, strm0 add ----
    __syncthreads();
    float* Obuf = (float*)smem;                 // 2 hh x 16KB
    float* Lbuf = (float*)(smem + 32768);       // 2 hh x 4KB
    if (strm == 1) {
        #pragma unroll
        for (int qt = 0; qt < 4; ++qt) {
            #pragma unroll
            for (int dt = 0; dt < 4; ++dt)
                ((float4v*)(Obuf + hh * 4096))[(qt * 4 + dt) * 64 + lane] = O[qt][dt];
            ((float4v*)(Lbuf + hh * 1024))[qt * 64 + lane] = O4[qt];
        }
    }
    __syncthreads();
    if (strm == 1) return;
    #pragma unroll
    for (int qt = 0; qt < 4; ++qt) {
        #pragma unroll
        for (int dt = 0; dt < 4; ++dt) {
            float4v o2 = ((float4v*)(Obuf + hh * 4096))[(qt * 4 + dt) * 64 + lane];
            O[qt][dt] += o2;
        }
        float4v l2 = ((float4v*)(Lbuf + hh * 1024))[qt * 64 + lane];
        O4[qt] += l2;
    }
    // epilogue: out = O / l  (l for this lane's quad rows sits in O4[qt][r])
    #pragma unroll
    for (int qt = 0; qt < 4; ++qt) {
        #pragma unroll
        for (int r = 0; r < 4; ++r) {
            float inv = 1.0f / O4[qt][r];
            int q = q0 + qt * 16 + quad * 4 + r;
            float* orow = out + ((size_t)(b * 2048 + q)) * 512 + h * 64;
            #pragma unroll
            for (int dt = 0; dt < 4; ++dt) orow[dt * 16 + li] = O[qt][dt][r] * inv;
        }
    }
}

extern "C" void kernel_launch(void* const* d_in, const int* in_sizes, int n_in,
                              void* d_out, int out_size, void* d_ws, size_t ws_size,
                              hipStream_t stream) {
    const float* x  = (const float*)d_in[0];
    const float* wq = (const float*)d_in[1];
    const float* wk = (const float*)d_in[2];
    const float* wv = (const float*)d_in[3];
    float* out = (float*)d_out;
    char* ws = (char*)d_ws;
    // ws layout (bytes): xh 8M | Wt 1.5M | Q 8M | K 8M | Vt 8M  = 35,127,296 total
    _Float16* xh = (_Float16*)(ws);
    _Float16* wt = (_Float16*)(ws + 8388608);
    _Float16* Qm = (_Float16*)(ws + 9961472);
    _Float16* Km = (_Float16*)(ws + 18350080);
    _Float16* Vt = (_Float16*)(ws + 26738688);
    if (ws_size < 35127296u) return;
    mha_prep<<<4288, 256, 0, stream>>>(x, wq, wk, wv, xh, wt);
    mha_qkv<<<768, 256, 0, stream>>>(xh, wt, Qm, Km, Vt);
    mha_attn<<<512, 256, 0, stream>>>(Qm, Km, Vt, out);
}